// Round 13
// baseline (5309.835 us; speedup 1.0000x reference)
//
#include <hip/hip_runtime.h>
#include <stdint.h>

typedef __attribute__((ext_vector_type(8))) short short8;
typedef __attribute__((ext_vector_type(4))) float fl4;
typedef __attribute__((ext_vector_type(2))) float fl2;
typedef __attribute__((ext_vector_type(8))) unsigned short us8;

#define SAT_HI 1.0e6f
#define ZSLOT 262144u            // elements per z slot (64*4096 bf16)

__device__ __forceinline__ unsigned short f2bf(float f) {
  unsigned u = __float_as_uint(f);
  u += 0x7fffu + ((u >> 16) & 1u);   // RNE
  return (unsigned short)(u >> 16);
}
__device__ __forceinline__ float clipf(float x) {
  return fminf(fmaxf(x, 0.0f), SAT_HI);
}

// per-wave wait on a producer counter line (relaxed agent poll, prompt detect)
__device__ __forceinline__ void gwait(const int* pgc, int target) {
  while (__hip_atomic_load(pgc, __ATOMIC_RELAXED, __HIP_MEMORY_SCOPE_AGENT) < target)
    __builtin_amdgcn_s_sleep(1);
  __builtin_amdgcn_sched_barrier(0);
}

// ---- pack W (f32 [N][N]) into bf16 MFMA B-fragments ----
// u = [ct:7][w:3][cf:1][ki:4][lane:6]; col-tile ct owns n in [32ct,32ct+32),
// wave w owns k in [512w,512w+512). lane: n = 32ct+16cf+(lane&15),
// k = 512w+32ki+8*(lane>>4). B[k][n] = W[n][k]  (y = z @ W^T)
__global__ __launch_bounds__(256) void prep_kernel(const float* __restrict__ W,
                                                   unsigned short* __restrict__ wfrag) {
  unsigned u = blockIdx.x * 256u + threadIdx.x;        // < 2097152
  unsigned lane = u & 63u, lo = lane & 15u, hi = lane >> 4;
  unsigned ki = (u >> 6) & 15u;
  unsigned cf = (u >> 10) & 1u;
  unsigned w = (u >> 11) & 7u;
  unsigned ct = u >> 14;               // 0..127
  unsigned n = ct * 32u + cf * 16u + lo;
  unsigned k = w * 512u + ki * 32u + hi * 8u;
  const float* src = W + (size_t)n * 4096u + k;
  fl4 s0 = *(const fl4*)(src);
  fl4 s1 = *(const fl4*)(src + 4);
  us8 o;
  o[0] = f2bf(s0[0]); o[1] = f2bf(s0[1]); o[2] = f2bf(s0[2]); o[3] = f2bf(s0[3]);
  o[4] = f2bf(s1[0]); o[5] = f2bf(s1[1]); o[6] = f2bf(s1[2]); o[7] = f2bf(s1[3]);
  *(us8*)(wfrag + (size_t)u * 8u) = o;
}

__global__ __launch_bounds__(512, 2) void persist_kernel(
    const float* __restrict__ xin,     // [C][B][T]
    const float* __restrict__ state0,  // [B][N]
    const float* __restrict__ mask,    // [N]
    const float* __restrict__ enc,     // [C][N]
    const float* __restrict__ bias,    // [N]
    const float* __restrict__ decw,    // [C][N]
    const unsigned short* __restrict__ wfrag,
    unsigned short* __restrict__ zbuf, // [R][B][N] bf16 ring
    float* __restrict__ dsc8,          // [8][C][B][T] f32, atomically accumulated
    int* __restrict__ cnt,             // [2][8][2] octet counters (32-int lines)
    int R, int invP) {
  // LDS: only the cross-wave partial exchange + decode staging (no z staging)
  __shared__ float pown[8][32][36];    // per-wave partials, pad 36 vs conflicts
  __shared__ float decbuf[8][32][4];   // decode results, flushed every 8 steps

  const int tid = threadIdx.x;
  const int wave = tid >> 6;           // 0..7, owns K-eighth
  const int lane = tid & 63;
  const int lo = lane & 15, hi = lane >> 4;
  const int g = blockIdx.x;
  const int rt = g & 1;                // row-half: rows [32rt, 32rt+32)
  const int ct = g >> 1;               // col-tile 0..127: cols [32ct, 32ct+32)
  float* dscg = dsc8 + (size_t)(ct & 7) * 131072u;
  // octet counters: 8 producer posts per line (halved RMW fan-in vs 16)
  int* mypgc = cnt + (rt * 16 + (ct >> 4) * 2 + ((ct >> 3) & 1)) * 32;
  int* wpgcA = cnt + (rt * 16 + wave * 2) * 32;
  int* wpgcB = wpgcA + 32;

  // persistent W fragments: 32 x short8 = 128 regs (AGPR-resident; wf[cf*16+ki])
  short8 wf[32];
  {
    const short8* wp = (const short8*)wfrag + (size_t)(ct * 8 + wave) * 32u * 64u + lane;
#pragma unroll
    for (int f = 0; f < 32; ++f) wf[f] = wp[(size_t)f * 64u];
  }

  // phase-B role: 2 outputs/thread: local row r = tid>>4, cols c2,c2+1
  const int r = tid >> 4, c2 = (tid & 15) * 2;
  const int b = rt * 32 + r;
  const int n0 = ct * 32 + c2;
  const fl2 mk = *(const fl2*)(mask + n0);
  const fl2 bi = *(const fl2*)(bias + n0);
  const fl2 e0 = *(const fl2*)(enc + n0);
  const fl2 e1 = *(const fl2*)(enc + 4096 + n0);
  const fl2 e2 = *(const fl2*)(enc + 8192 + n0);
  const fl2 e3 = *(const fl2*)(enc + 12288 + n0);
  const fl2 w0 = *(const fl2*)(decw + n0);
  const fl2 w1 = *(const fl2*)(decw + 4096 + n0);
  const fl2 w2 = *(const fl2*)(decw + 8192 + n0);
  const fl2 w3 = *(const fl2*)(decw + 12288 + n0);
  const float* xp = xin + b * 512;
  // wave's K-slice byte offset within a z row + this lane's sub-offset
  const size_t kwb = (size_t)wave * 1024u + (size_t)hi * 16u;
  const int rbase = rt * 32;

  // prologue: z_0 -> slot 0 (write-through), then post
  {
    fl2 st = *(const fl2*)(state0 + (size_t)b * 4096u + n0);
    float x0 = xp[0], x1 = xp[32768], x2 = xp[65536], x3 = xp[98304];
    float z0 = st[0] + mk[0] * (x0 * e0[0] + x1 * e1[0] + x2 * e2[0] + x3 * e3[0]);
    float z1 = st[1] + mk[1] * (x0 * e0[1] + x1 * e1[1] + x2 * e2[1] + x3 * e3[1]);
    unsigned pack = (unsigned)f2bf(z0) | ((unsigned)f2bf(z1) << 16);
    __hip_atomic_store((unsigned*)(zbuf + (size_t)b * 4096u + n0), pack,
                       __ATOMIC_RELAXED, __HIP_MEMORY_SCOPE_SYSTEM);
  }
  __syncthreads();                     // drains all waves' z stores
  if (tid == 0)
    __hip_atomic_fetch_add(mypgc, 1, __ATOMIC_RELAXED, __HIP_MEMORY_SCOPE_AGENT);

  int cur = 0;
  int invc = invP;
  for (int t = 0; t < 512; ++t) {
    // next-step x prefetch (retires under the poll's implicit drain)
    float xv0 = 0.f, xv1 = 0.f, xv2 = 0.f, xv3 = 0.f;
    if (t < 511) {
      xv0 = xp[t + 1]; xv1 = xp[32768 + t + 1];
      xv2 = xp[65536 + t + 1]; xv3 = xp[98304 + t + 1];
    }

    // ---- wait on THIS wave's two producer octets ----
    gwait(wpgcA, 8 * (t + 1));
    gwait(wpgcB, 8 * (t + 1));
    const char* zs = (const char*)(zbuf + (size_t)cur * ZSLOT) + kwb;
    // opaque touch: forbids hoisting the A-loads above the polls
    asm volatile("" : "+v"(zs));

    // ---- direct-to-register A-frags + MFMA (no LDS round-trip) ----
    // frag kk (k-granule 32): lane(lo,hi) reads z[row][bytes kk*64+hi*16 of
    // wave slice] — 16B contiguous; compiler pipelines loads under MFMAs.
    fl4 a00 = {0.f,0.f,0.f,0.f}, a01 = a00, a10 = a00, a11 = a00;
    {
      short8 a[16];
#pragma unroll
      for (int kk = 0; kk < 16; ++kk)
        a[kk] = *(const short8*)(zs + (size_t)(rbase + lo) * 8192u + kk * 64);
#pragma unroll
      for (int kk = 0; kk < 16; ++kk) {
        a00 = __builtin_amdgcn_mfma_f32_16x16x32_bf16(a[kk], wf[kk], a00, 0, 0, 0);
        a01 = __builtin_amdgcn_mfma_f32_16x16x32_bf16(a[kk], wf[16 + kk], a01, 0, 0, 0);
      }
#pragma unroll
      for (int kk = 0; kk < 16; ++kk)
        a[kk] = *(const short8*)(zs + (size_t)(rbase + 16 + lo) * 8192u + kk * 64);
#pragma unroll
      for (int kk = 0; kk < 16; ++kk) {
        a10 = __builtin_amdgcn_mfma_f32_16x16x32_bf16(a[kk], wf[kk], a10, 0, 0, 0);
        a11 = __builtin_amdgcn_mfma_f32_16x16x32_bf16(a[kk], wf[16 + kk], a11, 0, 0, 0);
      }
    }

    // ---- stash per-wave partials ----
#pragma unroll
    for (int rr = 0; rr < 4; ++rr) {
      pown[wave][hi * 4 + rr][lo] = a00[rr];
      pown[wave][hi * 4 + rr][16 + lo] = a01[rr];
      pown[wave][16 + hi * 4 + rr][lo] = a10[rr];
      pown[wave][16 + hi * 4 + rr][16 + lo] = a11[rr];
    }
    __syncthreads();

    // ---- phase B: reduce over 8 waves + state update ----
    float y0 = 0.f, y1 = 0.f;
#pragma unroll
    for (int w = 0; w < 8; ++w) {
      fl2 v = *(const fl2*)(&pown[w][r][c2]);
      y0 += v[0]; y1 += v[1];
    }
    float sn0 = mk[0] * (bi[0] + clipf(y0));
    float sn1 = mk[1] * (bi[1] + clipf(y1));

    // next z (critical path), write-through to next ring slot
    if (t < 511) {
      int ns = cur + 1; if (ns == R) ns = 0;
      float z0 = sn0 + mk[0] * (xv0 * e0[0] + xv1 * e1[0] + xv2 * e2[0] + xv3 * e3[0]);
      float z1 = sn1 + mk[1] * (xv0 * e0[1] + xv1 * e1[1] + xv2 * e2[1] + xv3 * e3[1]);
      unsigned pack = (unsigned)f2bf(z0) | ((unsigned)f2bf(z1) << 16);
      __hip_atomic_store((unsigned*)(zbuf + (size_t)ns * ZSLOT + (size_t)b * 4096u + n0),
                         pack, __ATOMIC_RELAXED, __HIP_MEMORY_SCOPE_SYSTEM);
      cur = ns;
    }
    __syncthreads();                   // drains ALL waves' z stores (+ pown reads done)

    if (t < 511 && tid == 0) {
      __hip_atomic_fetch_add(mypgc, 1, __ATOMIC_RELAXED, __HIP_MEMORY_SCOPE_AGENT);
      // periodic L2/L1 invalidation: ring reuses a slot every R steps; any
      // window of R steps contains an inv (invP = R-3 < R).
      if (--invc == 0) {
        invc = invP;
        (void)__hip_atomic_load(mypgc, __ATOMIC_ACQUIRE, __HIP_MEMORY_SCOPE_AGENT);
      }
    }

    // ---- decode reduce -> LDS (atomic flush every 8 steps, off-chain) ----
    float d0 = sn0 * w0[0] + sn1 * w0[1];
    float d1 = sn0 * w1[0] + sn1 * w1[1];
    float d2 = sn0 * w2[0] + sn1 * w2[1];
    float d3 = sn0 * w3[0] + sn1 * w3[1];
    d0 += __shfl_xor(d0, 1); d0 += __shfl_xor(d0, 2); d0 += __shfl_xor(d0, 4); d0 += __shfl_xor(d0, 8);
    d1 += __shfl_xor(d1, 1); d1 += __shfl_xor(d1, 2); d1 += __shfl_xor(d1, 4); d1 += __shfl_xor(d1, 8);
    d2 += __shfl_xor(d2, 1); d2 += __shfl_xor(d2, 2); d2 += __shfl_xor(d2, 4); d2 += __shfl_xor(d2, 8);
    d3 += __shfl_xor(d3, 1); d3 += __shfl_xor(d3, 2); d3 += __shfl_xor(d3, 4); d3 += __shfl_xor(d3, 8);
    if ((tid & 15) < 4) {
      const int ch = tid & 3;
      float dv = d0;
      if (ch == 1) dv = d1; else if (ch == 2) dv = d2; else if (ch == 3) dv = d3;
      decbuf[t & 7][r][ch] = dv;
    }
    if ((t & 7) == 7) {                // uniform condition, full groups (512%8==0)
      __syncthreads();
      if (tid < 128) {
        const int row = tid >> 2, ch = tid & 3;
        float* dp = dscg + ch * 32768 + (rbase + row) * 512 + (t - 7);
#pragma unroll
        for (int j = 0; j < 8; ++j)
          atomicAdd(dp + j, decbuf[j][row][ch]);
      }
      // flush atomics drain under the next gwait's poll (implicit vmcnt(0))
    }
  }
}

__global__ __launch_bounds__(256) void final_kernel(const float* __restrict__ dsc8,
                                                    const float* __restrict__ decb,
                                                    float* __restrict__ out) {
  const unsigned u = blockIdx.x * 256u + threadIdx.x;  // < 131072, [C][B][T]
  const unsigned c = u >> 15;
  float s = decb[c];
#pragma unroll
  for (int g = 0; g < 8; ++g) s += dsc8[(size_t)g * 131072u + u];
  out[u] = clipf(s);
}

extern "C" void kernel_launch(void* const* d_in, const int* in_sizes, int n_in,
                              void* d_out, int out_size, void* d_ws, size_t ws_size,
                              hipStream_t stream) {
  const float* xin  = (const float*)d_in[0];
  const float* st   = (const float*)d_in[1];
  const float* mask = (const float*)d_in[2];
  const float* W    = (const float*)d_in[3];
  const float* enc  = (const float*)d_in[4];
  const float* bias = (const float*)d_in[5];
  const float* decw = (const float*)d_in[6];
  const float* decb = (const float*)d_in[7];
  char* ws = (char*)d_ws;

  const size_t WFRAG_B = 33554432ull;             // 32 MB
  const size_t SLOT_B  = 524288ull;               // 512 KB per z slot
  const size_t DSC_B   = 4194304ull;              // 8 copies x 512 KB
  const size_t CNT_B   = 4096ull;
  const size_t fixed   = WFRAG_B + DSC_B + CNT_B;

  // R capped at 256: ring stays LLC-resident (128 MB); inv ~2x/block/run.
  int R = 4;
  if (ws_size > fixed) {
    size_t r = (ws_size - fixed) / SLOT_B;
    R = (r > 256) ? 256 : (int)r;
    if (R < 4) R = 4;
  }
  const int invP = R - 3;

  unsigned short* wfrag = (unsigned short*)(ws);
  unsigned short* zbuf  = (unsigned short*)(ws + WFRAG_B);
  float* dsc8 = (float*)(ws + WFRAG_B + (size_t)R * SLOT_B);
  int* cnt    = (int*)(ws + WFRAG_B + (size_t)R * SLOT_B + DSC_B);

  hipMemsetAsync(cnt, 0, CNT_B, stream);
  hipMemsetAsync(dsc8, 0, DSC_B, stream);
  prep_kernel<<<8192, 256, 0, stream>>>(W, wfrag);
  persist_kernel<<<256, 512, 0, stream>>>(xin, st, mask, enc, bias, decw,
                                          wfrag, zbuf, dsc8, cnt, R, invP);
  final_kernel<<<512, 256, 0, stream>>>(dsc8, decb, (float*)d_out);
}

// Round 14
// 4033.289 us; speedup vs baseline: 1.3165x; 1.3165x over previous
//
#include <hip/hip_runtime.h>
#include <stdint.h>

typedef __attribute__((ext_vector_type(8))) short short8;
typedef __attribute__((ext_vector_type(4))) float fl4;
typedef __attribute__((ext_vector_type(2))) float fl2;
typedef __attribute__((ext_vector_type(8))) unsigned short us8;

#define SAT_HI 1.0e6f
#define ZSLOT 262144u            // elements per z slot (64*4096 bf16)

__device__ __forceinline__ unsigned short f2bf(float f) {
  unsigned u = __float_as_uint(f);
  u += 0x7fffu + ((u >> 16) & 1u);   // RNE
  return (unsigned short)(u >> 16);
}
__device__ __forceinline__ float clipf(float x) {
  return fminf(fmaxf(x, 0.0f), SAT_HI);
}

__device__ __forceinline__ void gload16(const void* g, void* l) {
  __builtin_amdgcn_global_load_lds(
      (const __attribute__((address_space(1))) void*)g,
      (__attribute__((address_space(3))) void*)l, 16, 0, 0);
}

// stage one 8 KB chunk: 16 rows x 512 B (K-half h) via 8 row-pair gload16.
// LDS layout [16 rows][512 B], 16B-granule XOR-swizzled by row&7 (source-side).
__device__ __forceinline__ void stage_chunk(const char* zsrc, char* dst,
                                            int rows0, int h, int lane) {
#pragma unroll
  for (int i = 0; i < 8; ++i) {
    const int rl = 2 * i + (lane >> 5);                       // row in chunk
    const unsigned q = (unsigned)(lane & 31) ^ ((unsigned)rl & 7u);
    gload16(zsrc + (size_t)(rows0 + rl) * 8192 + h * 512 + (q << 4),
            dst + i * 1024);
  }
}

// per-wave wait on a producer counter line (relaxed agent poll, prompt detect)
__device__ __forceinline__ void gwait(const int* pgc, int target) {
  while (__hip_atomic_load(pgc, __ATOMIC_RELAXED, __HIP_MEMORY_SCOPE_AGENT) < target)
    __builtin_amdgcn_s_sleep(1);
  __builtin_amdgcn_sched_barrier(0);
}

#define MFMA_CHUNK(BUF, H, ACCA, ACCB)                                         \
  _Pragma("unroll")                                                            \
  for (int ki_ = 0; ki_ < 8; ++ki_) {                                          \
    short8 a_ = *(const short8*)((BUF) + lo * 512 +                            \
        ((((unsigned)(ki_ * 4 + hi)) ^ ((unsigned)lo & 7u)) << 4));            \
    ACCA = __builtin_amdgcn_mfma_f32_16x16x32_bf16(a_, wf[(H) * 8 + ki_], ACCA, 0, 0, 0); \
    ACCB = __builtin_amdgcn_mfma_f32_16x16x32_bf16(a_, wf[16 + (H) * 8 + ki_], ACCB, 0, 0, 0); \
  }

// ---- pack W (f32 [N][N]) into bf16 MFMA B-fragments ----
// u = [ct:7][w:3][cf:1][ki:4][lane:6]; col-tile ct owns n in [32ct,32ct+32),
// wave w owns k in [512w,512w+512). lane: n = 32ct+16cf+(lane&15),
// k = 512w+32ki+8*(lane>>4). B[k][n] = W[n][k]  (y = z @ W^T)
__global__ __launch_bounds__(256) void prep_kernel(const float* __restrict__ W,
                                                   unsigned short* __restrict__ wfrag) {
  unsigned u = blockIdx.x * 256u + threadIdx.x;        // < 2097152
  unsigned lane = u & 63u, lo = lane & 15u, hi = lane >> 4;
  unsigned ki = (u >> 6) & 15u;
  unsigned cf = (u >> 10) & 1u;
  unsigned w = (u >> 11) & 7u;
  unsigned ct = u >> 14;               // 0..127
  unsigned n = ct * 32u + cf * 16u + lo;
  unsigned k = w * 512u + ki * 32u + hi * 8u;
  const float* src = W + (size_t)n * 4096u + k;
  fl4 s0 = *(const fl4*)(src);
  fl4 s1 = *(const fl4*)(src + 4);
  us8 o;
  o[0] = f2bf(s0[0]); o[1] = f2bf(s0[1]); o[2] = f2bf(s0[2]); o[3] = f2bf(s0[3]);
  o[4] = f2bf(s1[0]); o[5] = f2bf(s1[1]); o[6] = f2bf(s1[2]); o[7] = f2bf(s1[3]);
  *(us8*)(wfrag + (size_t)u * 8u) = o;
}

__global__ __launch_bounds__(512, 2) void persist_kernel(
    const float* __restrict__ xin,     // [C][B][T]
    const float* __restrict__ state0,  // [B][N]
    const float* __restrict__ mask,    // [N]
    const float* __restrict__ enc,     // [C][N]
    const float* __restrict__ bias,    // [N]
    const float* __restrict__ decw,    // [C][N]
    const unsigned short* __restrict__ wfrag,
    unsigned short* __restrict__ zbuf, // [R][B][N] bf16 ring
    float* __restrict__ dsc8,          // [8][C][B][T] f32, atomically accumulated
    int* __restrict__ cnt,             // [2][8][2] octet counters (32-int lines)
    int R, int invP) {
  // 8 waves x (2 x 8 KB ping-pong stage buffers) = 128 KB; wave's f32 partial
  // block [32][36] (4608 B) aliases the head of its buf0 after consumption.
  __shared__ __align__(16) unsigned char sm[131072];
  // per-step decode results, flushed via atomics every 8 steps (off-chain)
  __shared__ float decbuf[8][32][4];

  const int tid = threadIdx.x;
  const int wave = tid >> 6;           // 0..7, owns K-eighth
  const int lane = tid & 63;
  const int lo = lane & 15, hi = lane >> 4;
  const int g = blockIdx.x;
  const int rt = g & 1;                // row-half: rows [32rt, 32rt+32)
  const int ct = g >> 1;               // col-tile 0..127: cols [32ct, 32ct+32)
  float* dscg = dsc8 + (size_t)(ct & 7) * 131072u;
  // octet counters: 8 producer posts per line (halved RMW fan-in vs 16)
  int* mypgc = cnt + (rt * 16 + (ct >> 4) * 2 + ((ct >> 3) & 1)) * 32;
  int* wpgcA = cnt + (rt * 16 + wave * 2) * 32;
  int* wpgcB = wpgcA + 32;

  // persistent W fragments: 32 x short8 = 128 regs (wf[cf*16+ki])
  short8 wf[32];
  {
    const short8* wp = (const short8*)wfrag + (size_t)(ct * 8 + wave) * 32u * 64u + lane;
#pragma unroll
    for (int f = 0; f < 32; ++f) wf[f] = wp[(size_t)f * 64u];
  }

  // phase-B role: 2 outputs/thread: local row r = tid>>4, cols c2,c2+1
  const int r = tid >> 4, c2 = (tid & 15) * 2;
  const int b = rt * 32 + r;
  const int n0 = ct * 32 + c2;
  const fl2 mk = *(const fl2*)(mask + n0);
  const fl2 bi = *(const fl2*)(bias + n0);
  const fl2 e0 = *(const fl2*)(enc + n0);
  const fl2 e1 = *(const fl2*)(enc + 4096 + n0);
  const fl2 e2 = *(const fl2*)(enc + 8192 + n0);
  const fl2 e3 = *(const fl2*)(enc + 12288 + n0);
  const fl2 w0 = *(const fl2*)(decw + n0);
  const fl2 w1 = *(const fl2*)(decw + 4096 + n0);
  const fl2 w2 = *(const fl2*)(decw + 8192 + n0);
  const fl2 w3 = *(const fl2*)(decw + 12288 + n0);
  const float* xp = xin + b * 512;
  const size_t kwb = (size_t)wave * 1024u;   // wave's K-slice byte offset in a z row
  const int rbase = rt * 32;

  char* buf0 = (char*)sm + wave * 16384;
  char* buf1 = buf0 + 8192;
  float* pown = (float*)buf0;          // aliased partial region [32][36] f32

  // prologue: z_0 -> slot 0 (write-through), then post
  {
    fl2 st = *(const fl2*)(state0 + (size_t)b * 4096u + n0);
    float x0 = xp[0], x1 = xp[32768], x2 = xp[65536], x3 = xp[98304];
    float z0 = st[0] + mk[0] * (x0 * e0[0] + x1 * e1[0] + x2 * e2[0] + x3 * e3[0]);
    float z1 = st[1] + mk[1] * (x0 * e0[1] + x1 * e1[1] + x2 * e2[1] + x3 * e3[1]);
    unsigned pack = (unsigned)f2bf(z0) | ((unsigned)f2bf(z1) << 16);
    __hip_atomic_store((unsigned*)(zbuf + (size_t)b * 4096u + n0), pack,
                       __ATOMIC_RELAXED, __HIP_MEMORY_SCOPE_SYSTEM);
  }
  __syncthreads();                     // drains all waves' z stores
  if (tid == 0)
    __hip_atomic_fetch_add(mypgc, 1, __ATOMIC_RELAXED, __HIP_MEMORY_SCOPE_AGENT);

  int cur = 0;
  int invc = invP;
  for (int t = 0; t < 512; ++t) {
    // next-step x prefetch (issued before the wait; poll's implicit vmcnt
    // drain retires it, so chain vmcnt counts below are unaffected)
    float xv0 = 0.f, xv1 = 0.f, xv2 = 0.f, xv3 = 0.f;
    if (t < 511) {
      xv0 = xp[t + 1]; xv1 = xp[32768 + t + 1];
      xv2 = xp[65536 + t + 1]; xv3 = xp[98304 + t + 1];
    }

    // ---- wait on THIS wave's two producer octets ----
    gwait(wpgcA, 8 * (t + 1));
    gwait(wpgcB, 8 * (t + 1));
    const char* zsrc = (const char*)(zbuf + (size_t)cur * ZSLOT) + kwb;

    // ---- pipelined staging (counted vmcnt, ping-pong 2x8KB) + MFMA ----
    fl4 a00 = {0.f,0.f,0.f,0.f}, a01 = a00, a10 = a00, a11 = a00;
    stage_chunk(zsrc, buf0, rbase, 0, lane);        // C0 (h0, rows 0-15)
    stage_chunk(zsrc, buf1, rbase + 16, 0, lane);   // C1 (h0, rows 16-31)
    asm volatile("s_waitcnt vmcnt(8)" ::: "memory");   // C0 ready
    __builtin_amdgcn_sched_barrier(0);
    MFMA_CHUNK(buf0, 0, a00, a01);
    asm volatile("s_waitcnt lgkmcnt(0)" ::: "memory");
    __builtin_amdgcn_sched_barrier(0);
    stage_chunk(zsrc, buf0, rbase, 1, lane);        // C2 (h1, rows 0-15)
    asm volatile("s_waitcnt vmcnt(8)" ::: "memory");   // C1 ready
    __builtin_amdgcn_sched_barrier(0);
    MFMA_CHUNK(buf1, 0, a10, a11);
    asm volatile("s_waitcnt lgkmcnt(0)" ::: "memory");
    __builtin_amdgcn_sched_barrier(0);
    stage_chunk(zsrc, buf1, rbase + 16, 1, lane);   // C3 (h1, rows 16-31)
    asm volatile("s_waitcnt vmcnt(8)" ::: "memory");   // C2 ready
    __builtin_amdgcn_sched_barrier(0);
    MFMA_CHUNK(buf0, 1, a00, a01);
    asm volatile("s_waitcnt vmcnt(0)" ::: "memory");   // C3 ready
    __builtin_amdgcn_sched_barrier(0);
    MFMA_CHUNK(buf1, 1, a10, a11);
    asm volatile("s_waitcnt lgkmcnt(0)" ::: "memory");
    __builtin_amdgcn_sched_barrier(0);

    // ---- stash per-wave partials [32][36] into own buf0 head ----
#pragma unroll
    for (int rr = 0; rr < 4; ++rr) {
      pown[(hi * 4 + rr) * 36 + lo] = a00[rr];
      pown[(hi * 4 + rr) * 36 + 16 + lo] = a01[rr];
      pown[(16 + hi * 4 + rr) * 36 + lo] = a10[rr];
      pown[(16 + hi * 4 + rr) * 36 + 16 + lo] = a11[rr];
    }
    __syncthreads();

    // ---- phase B: reduce over 8 waves + state update ----
    float y0 = 0.f, y1 = 0.f;
#pragma unroll
    for (int w = 0; w < 8; ++w) {
      fl2 v = *(const fl2*)((const char*)sm + w * 16384 + (size_t)(r * 36 + c2) * 4u);
      y0 += v[0]; y1 += v[1];
    }
    float sn0 = mk[0] * (bi[0] + clipf(y0));
    float sn1 = mk[1] * (bi[1] + clipf(y1));

    // next z (critical path), write-through to next ring slot
    if (t < 511) {
      int ns = cur + 1; if (ns == R) ns = 0;
      float z0 = sn0 + mk[0] * (xv0 * e0[0] + xv1 * e1[0] + xv2 * e2[0] + xv3 * e3[0]);
      float z1 = sn1 + mk[1] * (xv0 * e0[1] + xv1 * e1[1] + xv2 * e2[1] + xv3 * e3[1]);
      unsigned pack = (unsigned)f2bf(z0) | ((unsigned)f2bf(z1) << 16);
      __hip_atomic_store((unsigned*)(zbuf + (size_t)ns * ZSLOT + (size_t)b * 4096u + n0),
                         pack, __ATOMIC_RELAXED, __HIP_MEMORY_SCOPE_SYSTEM);
      cur = ns;
    }
    __syncthreads();                   // drains ALL waves' z stores (+ pown reads done)

    if (t < 511) {
      // post on tid0 (critical); periodic inv delegated to tid256 so the
      // posting wave never stalls on cache maintenance (same CU L1/XCD L2).
      if (tid == 0)
        __hip_atomic_fetch_add(mypgc, 1, __ATOMIC_RELAXED, __HIP_MEMORY_SCOPE_AGENT);
      if (tid == 256 && --invc == 0) {
        invc = invP;
        (void)__hip_atomic_load(mypgc, __ATOMIC_ACQUIRE, __HIP_MEMORY_SCOPE_AGENT);
      }
    }

    // ---- decode reduce -> LDS (atomic flush every 8 steps, off-chain) ----
    float d0 = sn0 * w0[0] + sn1 * w0[1];
    float d1 = sn0 * w1[0] + sn1 * w1[1];
    float d2 = sn0 * w2[0] + sn1 * w2[1];
    float d3 = sn0 * w3[0] + sn1 * w3[1];
    d0 += __shfl_xor(d0, 1); d0 += __shfl_xor(d0, 2); d0 += __shfl_xor(d0, 4); d0 += __shfl_xor(d0, 8);
    d1 += __shfl_xor(d1, 1); d1 += __shfl_xor(d1, 2); d1 += __shfl_xor(d1, 4); d1 += __shfl_xor(d1, 8);
    d2 += __shfl_xor(d2, 1); d2 += __shfl_xor(d2, 2); d2 += __shfl_xor(d2, 4); d2 += __shfl_xor(d2, 8);
    d3 += __shfl_xor(d3, 1); d3 += __shfl_xor(d3, 2); d3 += __shfl_xor(d3, 4); d3 += __shfl_xor(d3, 8);
    if ((tid & 15) < 4) {
      const int ch = tid & 3;
      float dv = d0;
      if (ch == 1) dv = d1; else if (ch == 2) dv = d2; else if (ch == 3) dv = d3;
      decbuf[t & 7][r][ch] = dv;
    }
    if ((t & 7) == 7) {                // uniform condition, full groups (512%8==0)
      __syncthreads();
      if (tid < 128) {
        const int row = tid >> 2, ch = tid & 3;
        float* dp = dscg + ch * 32768 + (rbase + row) * 512 + (t - 7);
#pragma unroll
        for (int j = 0; j < 8; ++j)
          atomicAdd(dp + j, decbuf[j][row][ch]);
      }
      // flush atomics drain under the next gwait's poll (implicit vmcnt(0))
    }
  }
}

__global__ __launch_bounds__(256) void final_kernel(const float* __restrict__ dsc8,
                                                    const float* __restrict__ decb,
                                                    float* __restrict__ out) {
  const unsigned u = blockIdx.x * 256u + threadIdx.x;  // < 131072, [C][B][T]
  const unsigned c = u >> 15;
  float s = decb[c];
#pragma unroll
  for (int g = 0; g < 8; ++g) s += dsc8[(size_t)g * 131072u + u];
  out[u] = clipf(s);
}

extern "C" void kernel_launch(void* const* d_in, const int* in_sizes, int n_in,
                              void* d_out, int out_size, void* d_ws, size_t ws_size,
                              hipStream_t stream) {
  const float* xin  = (const float*)d_in[0];
  const float* st   = (const float*)d_in[1];
  const float* mask = (const float*)d_in[2];
  const float* W    = (const float*)d_in[3];
  const float* enc  = (const float*)d_in[4];
  const float* bias = (const float*)d_in[5];
  const float* decw = (const float*)d_in[6];
  const float* decb = (const float*)d_in[7];
  char* ws = (char*)d_ws;

  const size_t WFRAG_B = 33554432ull;             // 32 MB
  const size_t SLOT_B  = 524288ull;               // 512 KB per z slot
  const size_t DSC_B   = 4194304ull;              // 8 copies x 512 KB
  const size_t CNT_B   = 4096ull;
  const size_t fixed   = WFRAG_B + DSC_B + CNT_B;

  // R capped at 256: ring stays LLC-resident (128 MB); inv ~2x/block/run.
  int R = 4;
  if (ws_size > fixed) {
    size_t r = (ws_size - fixed) / SLOT_B;
    R = (r > 256) ? 256 : (int)r;
    if (R < 4) R = 4;
  }
  const int invP = R - 3;

  unsigned short* wfrag = (unsigned short*)(ws);
  unsigned short* zbuf  = (unsigned short*)(ws + WFRAG_B);
  float* dsc8 = (float*)(ws + WFRAG_B + (size_t)R * SLOT_B);
  int* cnt    = (int*)(ws + WFRAG_B + (size_t)R * SLOT_B + DSC_B);

  hipMemsetAsync(cnt, 0, CNT_B, stream);
  hipMemsetAsync(dsc8, 0, DSC_B, stream);
  prep_kernel<<<8192, 256, 0, stream>>>(W, wfrag);
  persist_kernel<<<256, 512, 0, stream>>>(xin, st, mask, enc, bias, decw,
                                          wfrag, zbuf, dsc8, cnt, R, invP);
  final_kernel<<<512, 256, 0, stream>>>(dsc8, decb, (float*)d_out);
}

// Round 15
// 3853.872 us; speedup vs baseline: 1.3778x; 1.0466x over previous
//
#include <hip/hip_runtime.h>
#include <stdint.h>

typedef __attribute__((ext_vector_type(8))) short short8;
typedef __attribute__((ext_vector_type(4))) float fl4;
typedef __attribute__((ext_vector_type(2))) float fl2;
typedef __attribute__((ext_vector_type(8))) unsigned short us8;

#define SAT_HI 1.0e6f
#define ZSLOT 262144u            // elements per z slot (64*4096 bf16)

__device__ __forceinline__ unsigned short f2bf(float f) {
  unsigned u = __float_as_uint(f);
  u += 0x7fffu + ((u >> 16) & 1u);   // RNE
  return (unsigned short)(u >> 16);
}
__device__ __forceinline__ float clipf(float x) {
  return fminf(fmaxf(x, 0.0f), SAT_HI);
}

__device__ __forceinline__ void gload16(const void* g, void* l) {
  __builtin_amdgcn_global_load_lds(
      (const __attribute__((address_space(1))) void*)g,
      (__attribute__((address_space(3))) void*)l, 16, 0, 0);
}

// stage one 8 KB chunk: 16 rows x 512 B (K-half h) via 8 row-pair gload16.
// LDS layout [16 rows][512 B], 16B-granule XOR-swizzled by row&7 (source-side).
__device__ __forceinline__ void stage_chunk(const char* zsrc, char* dst,
                                            int rows0, int h, int lane) {
#pragma unroll
  for (int i = 0; i < 8; ++i) {
    const int rl = 2 * i + (lane >> 5);                       // row in chunk
    const unsigned q = (unsigned)(lane & 31) ^ ((unsigned)rl & 7u);
    gload16(zsrc + (size_t)(rows0 + rl) * 8192 + h * 512 + (q << 4),
            dst + i * 1024);
  }
}

// per-wave wait on a producer-group counter (relaxed agent poll).
// Prompt detection beats poll cheapness: the chain advances at post->detect
// speed (r11 backoff regressed; r14 two-line octet split regressed).
__device__ __forceinline__ void gwait(const int* pgc, int target) {
  while (__hip_atomic_load(pgc, __ATOMIC_RELAXED, __HIP_MEMORY_SCOPE_AGENT) < target)
    __builtin_amdgcn_s_sleep(1);
  __builtin_amdgcn_sched_barrier(0);
}

#define MFMA_CHUNK(BUF, H, ACCA, ACCB)                                         \
  _Pragma("unroll")                                                            \
  for (int ki_ = 0; ki_ < 8; ++ki_) {                                          \
    short8 a_ = *(const short8*)((BUF) + lo * 512 +                            \
        ((((unsigned)(ki_ * 4 + hi)) ^ ((unsigned)lo & 7u)) << 4));            \
    ACCA = __builtin_amdgcn_mfma_f32_16x16x32_bf16(a_, wf[(H) * 8 + ki_], ACCA, 0, 0, 0); \
    ACCB = __builtin_amdgcn_mfma_f32_16x16x32_bf16(a_, wf[16 + (H) * 8 + ki_], ACCB, 0, 0, 0); \
  }

// ---- pack W (f32 [N][N]) into bf16 MFMA B-fragments ----
// u = [ct:7][w:3][cf:1][ki:4][lane:6]; col-tile ct owns n in [32ct,32ct+32),
// wave w owns k in [512w,512w+512). lane: n = 32ct+16cf+(lane&15),
// k = 512w+32ki+8*(lane>>4). B[k][n] = W[n][k]  (y = z @ W^T)
__global__ __launch_bounds__(256) void prep_kernel(const float* __restrict__ W,
                                                   unsigned short* __restrict__ wfrag) {
  unsigned u = blockIdx.x * 256u + threadIdx.x;        // < 2097152
  unsigned lane = u & 63u, lo = lane & 15u, hi = lane >> 4;
  unsigned ki = (u >> 6) & 15u;
  unsigned cf = (u >> 10) & 1u;
  unsigned w = (u >> 11) & 7u;
  unsigned ct = u >> 14;               // 0..127
  unsigned n = ct * 32u + cf * 16u + lo;
  unsigned k = w * 512u + ki * 32u + hi * 8u;
  const float* src = W + (size_t)n * 4096u + k;
  fl4 s0 = *(const fl4*)(src);
  fl4 s1 = *(const fl4*)(src + 4);
  us8 o;
  o[0] = f2bf(s0[0]); o[1] = f2bf(s0[1]); o[2] = f2bf(s0[2]); o[3] = f2bf(s0[3]);
  o[4] = f2bf(s1[0]); o[5] = f2bf(s1[1]); o[6] = f2bf(s1[2]); o[7] = f2bf(s1[3]);
  *(us8*)(wfrag + (size_t)u * 8u) = o;
}

__global__ __launch_bounds__(512, 2) void persist_kernel(
    const float* __restrict__ xin,     // [C][B][T]
    const float* __restrict__ state0,  // [B][N]
    const float* __restrict__ mask,    // [N]
    const float* __restrict__ enc,     // [C][N]
    const float* __restrict__ bias,    // [N]
    const float* __restrict__ decw,    // [C][N]
    const unsigned short* __restrict__ wfrag,
    unsigned short* __restrict__ zbuf, // [R][B][N] bf16 ring
    float* __restrict__ dsc8,          // [8][C][B][T] f32, atomically accumulated
    int* __restrict__ cnt,             // [2][8] producer-group counters (32-int lines)
    int R, int invP) {
  // 8 waves x (2 x 8 KB ping-pong stage buffers) = 128 KB; wave's f32 partial
  // block [32][36] (4608 B) aliases the head of its buf0 after consumption.
  __shared__ __align__(16) unsigned char sm[131072];
  // per-step decode results, flushed via atomics every 8 steps (off-chain)
  __shared__ float decbuf[8][32][4];

  const int tid = threadIdx.x;
  const int wave = tid >> 6;           // 0..7, owns K-eighth
  const int lane = tid & 63;
  const int lo = lane & 15, hi = lane >> 4;
  const int g = blockIdx.x;
  const int rt = g & 1;                // row-half: rows [32rt, 32rt+32)
  const int ct = g >> 1;               // col-tile 0..127: cols [32ct, 32ct+32)
  float* dscg = dsc8 + (size_t)(ct & 7) * 131072u;
  int* mypgc = cnt + (rt * 8 + (ct >> 4)) * 32;  // this block posts here
  int* wpgc  = cnt + (rt * 8 + wave) * 32;       // this wave waits here

  // persistent W fragments: 32 x short8 = 128 regs (wf[cf*16+ki])
  short8 wf[32];
  {
    const short8* wp = (const short8*)wfrag + (size_t)(ct * 8 + wave) * 32u * 64u + lane;
#pragma unroll
    for (int f = 0; f < 32; ++f) wf[f] = wp[(size_t)f * 64u];
  }

  // phase-B role: 2 outputs/thread: local row r = tid>>4, cols c2,c2+1
  const int r = tid >> 4, c2 = (tid & 15) * 2;
  const int b = rt * 32 + r;
  const int n0 = ct * 32 + c2;
  const fl2 mk = *(const fl2*)(mask + n0);
  const fl2 bi = *(const fl2*)(bias + n0);
  const fl2 e0 = *(const fl2*)(enc + n0);
  const fl2 e1 = *(const fl2*)(enc + 4096 + n0);
  const fl2 e2 = *(const fl2*)(enc + 8192 + n0);
  const fl2 e3 = *(const fl2*)(enc + 12288 + n0);
  const fl2 w0 = *(const fl2*)(decw + n0);
  const fl2 w1 = *(const fl2*)(decw + 4096 + n0);
  const fl2 w2 = *(const fl2*)(decw + 8192 + n0);
  const fl2 w3 = *(const fl2*)(decw + 12288 + n0);
  const float* xp = xin + b * 512;
  const size_t kwb = (size_t)wave * 1024u;   // wave's K-slice byte offset in a z row
  const int rbase = rt * 32;

  char* buf0 = (char*)sm + wave * 16384;
  char* buf1 = buf0 + 8192;
  float* pown = (float*)buf0;          // aliased partial region [32][36] f32

  // prologue: z_0 -> slot 0 (write-through), then post
  {
    fl2 st = *(const fl2*)(state0 + (size_t)b * 4096u + n0);
    float x0 = xp[0], x1 = xp[32768], x2 = xp[65536], x3 = xp[98304];
    float z0 = st[0] + mk[0] * (x0 * e0[0] + x1 * e1[0] + x2 * e2[0] + x3 * e3[0]);
    float z1 = st[1] + mk[1] * (x0 * e0[1] + x1 * e1[1] + x2 * e2[1] + x3 * e3[1]);
    unsigned pack = (unsigned)f2bf(z0) | ((unsigned)f2bf(z1) << 16);
    __hip_atomic_store((unsigned*)(zbuf + (size_t)b * 4096u + n0), pack,
                       __ATOMIC_RELAXED, __HIP_MEMORY_SCOPE_SYSTEM);
  }
  __syncthreads();                     // drains all waves' z stores
  if (tid == 0)
    __hip_atomic_fetch_add(mypgc, 1, __ATOMIC_RELAXED, __HIP_MEMORY_SCOPE_AGENT);

  int cur = 0;
  int invc = invP;
  for (int t = 0; t < 512; ++t) {
    // next-step x prefetch (issued before the wait; poll's implicit vmcnt
    // drain retires it, so chain vmcnt counts below are unaffected)
    float xv0 = 0.f, xv1 = 0.f, xv2 = 0.f, xv3 = 0.f;
    if (t < 511) {
      xv0 = xp[t + 1]; xv1 = xp[32768 + t + 1];
      xv2 = xp[65536 + t + 1]; xv3 = xp[98304 + t + 1];
    }

    // ---- wait only on THIS wave's 16 producers ----
    gwait(wpgc, 16 * (t + 1));
    const char* zsrc = (const char*)(zbuf + (size_t)cur * ZSLOT) + kwb;

    // ---- pipelined staging (counted vmcnt, ping-pong 2x8KB) + MFMA ----
    // No atomics inside the chain: counts are pure chunk arithmetic.
    fl4 a00 = {0.f,0.f,0.f,0.f}, a01 = a00, a10 = a00, a11 = a00;
    stage_chunk(zsrc, buf0, rbase, 0, lane);        // C0 (h0, rows 0-15)
    stage_chunk(zsrc, buf1, rbase + 16, 0, lane);   // C1 (h0, rows 16-31)
    asm volatile("s_waitcnt vmcnt(8)" ::: "memory");   // C0 ready
    __builtin_amdgcn_sched_barrier(0);
    MFMA_CHUNK(buf0, 0, a00, a01);
    asm volatile("s_waitcnt lgkmcnt(0)" ::: "memory");
    __builtin_amdgcn_sched_barrier(0);
    stage_chunk(zsrc, buf0, rbase, 1, lane);        // C2 (h1, rows 0-15)
    asm volatile("s_waitcnt vmcnt(8)" ::: "memory");   // C1 ready
    __builtin_amdgcn_sched_barrier(0);
    MFMA_CHUNK(buf1, 0, a10, a11);
    asm volatile("s_waitcnt lgkmcnt(0)" ::: "memory");
    __builtin_amdgcn_sched_barrier(0);
    stage_chunk(zsrc, buf1, rbase + 16, 1, lane);   // C3 (h1, rows 16-31)
    asm volatile("s_waitcnt vmcnt(8)" ::: "memory");   // C2 ready
    __builtin_amdgcn_sched_barrier(0);
    MFMA_CHUNK(buf0, 1, a00, a01);
    asm volatile("s_waitcnt vmcnt(0)" ::: "memory");   // C3 ready
    __builtin_amdgcn_sched_barrier(0);
    MFMA_CHUNK(buf1, 1, a10, a11);
    asm volatile("s_waitcnt lgkmcnt(0)" ::: "memory");
    __builtin_amdgcn_sched_barrier(0);

    // ---- stash per-wave partials [32][36] into own buf0 head ----
#pragma unroll
    for (int rr = 0; rr < 4; ++rr) {
      pown[(hi * 4 + rr) * 36 + lo] = a00[rr];
      pown[(hi * 4 + rr) * 36 + 16 + lo] = a01[rr];
      pown[(16 + hi * 4 + rr) * 36 + lo] = a10[rr];
      pown[(16 + hi * 4 + rr) * 36 + 16 + lo] = a11[rr];
    }
    __syncthreads();

    // ---- phase B: reduce over 8 waves + state update ----
    float y0 = 0.f, y1 = 0.f;
#pragma unroll
    for (int w = 0; w < 8; ++w) {
      fl2 v = *(const fl2*)((const char*)sm + w * 16384 + (size_t)(r * 36 + c2) * 4u);
      y0 += v[0]; y1 += v[1];
    }
    float sn0 = mk[0] * (bi[0] + clipf(y0));
    float sn1 = mk[1] * (bi[1] + clipf(y1));

    // next z (critical path), write-through to next ring slot
    if (t < 511) {
      int ns = cur + 1; if (ns == R) ns = 0;
      float z0 = sn0 + mk[0] * (xv0 * e0[0] + xv1 * e1[0] + xv2 * e2[0] + xv3 * e3[0]);
      float z1 = sn1 + mk[1] * (xv0 * e0[1] + xv1 * e1[1] + xv2 * e2[1] + xv3 * e3[1]);
      unsigned pack = (unsigned)f2bf(z0) | ((unsigned)f2bf(z1) << 16);
      __hip_atomic_store((unsigned*)(zbuf + (size_t)ns * ZSLOT + (size_t)b * 4096u + n0),
                         pack, __ATOMIC_RELAXED, __HIP_MEMORY_SCOPE_SYSTEM);
      cur = ns;
    }
    __syncthreads();                   // drains ALL waves' z stores (+ pown reads done)

    if (t < 511 && tid == 0) {
      __hip_atomic_fetch_add(mypgc, 1, __ATOMIC_RELAXED, __HIP_MEMORY_SCOPE_AGENT);
      // periodic L2/L1 invalidation: ring reuses a slot every R steps; any
      // window of R steps contains an inv (invP = R-3 < R).
      if (--invc == 0) {
        invc = invP;
        (void)__hip_atomic_load(mypgc, __ATOMIC_ACQUIRE, __HIP_MEMORY_SCOPE_AGENT);
      }
    }

    // ---- decode reduce -> LDS (atomic flush every 8 steps, off-chain) ----
    float d0 = sn0 * w0[0] + sn1 * w0[1];
    float d1 = sn0 * w1[0] + sn1 * w1[1];
    float d2 = sn0 * w2[0] + sn1 * w2[1];
    float d3 = sn0 * w3[0] + sn1 * w3[1];
    d0 += __shfl_xor(d0, 1); d0 += __shfl_xor(d0, 2); d0 += __shfl_xor(d0, 4); d0 += __shfl_xor(d0, 8);
    d1 += __shfl_xor(d1, 1); d1 += __shfl_xor(d1, 2); d1 += __shfl_xor(d1, 4); d1 += __shfl_xor(d1, 8);
    d2 += __shfl_xor(d2, 1); d2 += __shfl_xor(d2, 2); d2 += __shfl_xor(d2, 4); d2 += __shfl_xor(d2, 8);
    d3 += __shfl_xor(d3, 1); d3 += __shfl_xor(d3, 2); d3 += __shfl_xor(d3, 4); d3 += __shfl_xor(d3, 8);
    if ((tid & 15) < 4) {
      const int ch = tid & 3;
      float dv = d0;
      if (ch == 1) dv = d1; else if (ch == 2) dv = d2; else if (ch == 3) dv = d3;
      decbuf[t & 7][r][ch] = dv;
    }
    if ((t & 7) == 7) {                // uniform condition, full groups (512%8==0)
      __syncthreads();
      if (tid < 128) {
        const int row = tid >> 2, ch = tid & 3;
        float* dp = dscg + ch * 32768 + (rbase + row) * 512 + (t - 7);
#pragma unroll
        for (int j = 0; j < 8; ++j)
          atomicAdd(dp + j, decbuf[j][row][ch]);
      }
      // flush atomics drain under the next gwait's poll (implicit vmcnt(0))
    }
  }
}

__global__ __launch_bounds__(256) void final_kernel(const float* __restrict__ dsc8,
                                                    const float* __restrict__ decb,
                                                    float* __restrict__ out) {
  const unsigned u = blockIdx.x * 256u + threadIdx.x;  // < 131072, [C][B][T]
  const unsigned c = u >> 15;
  float s = decb[c];
#pragma unroll
  for (int g = 0; g < 8; ++g) s += dsc8[(size_t)g * 131072u + u];
  out[u] = clipf(s);
}

extern "C" void kernel_launch(void* const* d_in, const int* in_sizes, int n_in,
                              void* d_out, int out_size, void* d_ws, size_t ws_size,
                              hipStream_t stream) {
  const float* xin  = (const float*)d_in[0];
  const float* st   = (const float*)d_in[1];
  const float* mask = (const float*)d_in[2];
  const float* W    = (const float*)d_in[3];
  const float* enc  = (const float*)d_in[4];
  const float* bias = (const float*)d_in[5];
  const float* decw = (const float*)d_in[6];
  const float* decb = (const float*)d_in[7];
  char* ws = (char*)d_ws;

  const size_t WFRAG_B = 33554432ull;             // 32 MB
  const size_t SLOT_B  = 524288ull;               // 512 KB per z slot
  const size_t DSC_B   = 4194304ull;              // 8 copies x 512 KB
  const size_t CNT_B   = 4096ull;
  const size_t fixed   = WFRAG_B + DSC_B + CNT_B;

  // R capped at 256: ring stays LLC-resident (128 MB); inv ~2x/block/run.
  int R = 4;
  if (ws_size > fixed) {
    size_t r = (ws_size - fixed) / SLOT_B;
    R = (r > 256) ? 256 : (int)r;
    if (R < 4) R = 4;
  }
  const int invP = R - 3;

  unsigned short* wfrag = (unsigned short*)(ws);
  unsigned short* zbuf  = (unsigned short*)(ws + WFRAG_B);
  float* dsc8 = (float*)(ws + WFRAG_B + (size_t)R * SLOT_B);
  int* cnt    = (int*)(ws + WFRAG_B + (size_t)R * SLOT_B + DSC_B);

  hipMemsetAsync(cnt, 0, CNT_B, stream);
  hipMemsetAsync(dsc8, 0, DSC_B, stream);
  prep_kernel<<<8192, 256, 0, stream>>>(W, wfrag);
  persist_kernel<<<256, 512, 0, stream>>>(xin, st, mask, enc, bias, decw,
                                          wfrag, zbuf, dsc8, cnt, R, invP);
  final_kernel<<<512, 256, 0, stream>>>(dsc8, decb, (float*)d_out);
}